// Round 9
// baseline (652.999 us; speedup 1.0000x reference)
//
#include <hip/hip_runtime.h>
#include <math.h>

#define NPTS 400000
#define NBATCH 8
#define K_OUT 64
#define IDX_SENTINEL 0x7fffffff

#define PPW 384                       // points per wave (6 iters of 64)
#define WPB_X 261                     // ceil(ceil(400000/384)/4)
#define LPB (WPB_X * 4)               // candidate lists per batch (=1044)

// wbuf layout (floats): [0..511] W1^T [c][o]; [512..639] W2^T [c][o];
// [640..655] b1; [656..663] b2; [664..671] W3; [672] b3
#define WB_W2 512
#define WB_B1 640
#define WB_B2 656
#define WB_W3 664
#define WB_B3 672

typedef float __attribute__((ext_vector_type(4))) f32x4;

// comparator: (value desc, index asc) — matches jax.lax.top_k tie-breaking
__device__ __forceinline__ bool better(float av, int ai, float bv, int bi) {
    return (av > bv) || (av == bv && ai < bi);
}

__device__ __forceinline__ void cmp_swap(float& v, int& i, int j, bool keepBetter) {
    float ov = __shfl_xor(v, j);
    int   oi = __shfl_xor(i, j);
    bool ob = better(ov, oi, v, i);
    if (keepBetter ? ob : !ob) { v = ov; i = oi; }
}

// Maintain per-wave top-64 (1 entry/lane, sorted descending by comparator).
__device__ __forceinline__ void wave_topk_insert(float& bv, int& bi, float nv, int ni, int lane) {
    float tv = __shfl(bv, 63);
    int   ti = __shfl(bi, 63);
    if (__ballot(better(nv, ni, tv, ti)) == 0ULL) return;
#pragma unroll
    for (int k = 2; k <= 64; k <<= 1) {
#pragma unroll
        for (int j = k >> 1; j > 0; j >>= 1) {
            bool keepBetter = (((lane & k) == 0) == ((lane & j) == 0));
            cmp_swap(nv, ni, j, keepBetter);
        }
    }
    float rv = __shfl(nv, lane ^ 63);
    int   ri = __shfl(ni, lane ^ 63);
    if (better(rv, ri, bv, bi)) { bv = rv; bi = ri; }
#pragma unroll
    for (int j = 32; j > 0; j >>= 1) cmp_swap(bv, bi, j, (lane & j) == 0);
}

__global__ __launch_bounds__(256) void prep_weights(
    const float* __restrict__ W1, const float* __restrict__ b1,
    const float* __restrict__ W2, const float* __restrict__ b2,
    const float* __restrict__ W3, const float* __restrict__ b3,
    float* __restrict__ wbuf)
{
    int t = threadIdx.x;
    for (int i = t; i < 512; i += 256) wbuf[i] = W1[(i & 15) * 32 + (i >> 4)];
    if (t < 128) wbuf[WB_W2 + t] = W2[(t & 7) * 16 + (t >> 3)];
    if (t < 16)       wbuf[WB_B1 + t] = b1[t];
    else if (t < 24)  wbuf[WB_B2 + (t - 16)] = b2[t - 16];
    else if (t < 32)  wbuf[WB_W3 + (t - 24)] = W3[t - 24];
    else if (t == 32) wbuf[WB_B3] = b3[0];
}

// Fused MLP + per-wave top-64 (R5 structure, unchanged — best so far).
__global__ __launch_bounds__(256, 8) void mlp_topk_fused(
    const float* __restrict__ X, const float* __restrict__ wb,
    int2* __restrict__ cand)
{
    int t = threadIdx.x;
    int b = blockIdx.y;
    int wave = blockIdx.x * 4 + (t >> 6);
    int lane = t & 63;
    const float* Xb = X + (size_t)b * 32 * NPTS;

    float bv = -INFINITY;
    int   bi = IDX_SENTINEL;
    int waveStart = wave * PPW;

#pragma unroll 1
    for (int it = 0; it < PPW / 64; ++it) {
        int nb = waveStart + it * 64;
        if (nb >= NPTS) break;
        int n = nb + lane;
        const float* p = Xb + n;

        float xA[8], xB[8];
        float a1[16];
#pragma unroll
        for (int o = 0; o < 16; ++o) a1[o] = 0.f;

#pragma unroll
        for (int j = 0; j < 8; ++j) xA[j] = p[(size_t)(0 + j) * NPTS];
#pragma unroll
        for (int j = 0; j < 8; ++j) xB[j] = p[(size_t)(8 + j) * NPTS];
#pragma unroll
        for (int j = 0; j < 8; ++j) {
            float x = xA[j];
#pragma unroll
            for (int o = 0; o < 16; ++o) a1[o] = fmaf(wb[(0 + j) * 16 + o], x, a1[o]);
        }
#pragma unroll
        for (int j = 0; j < 8; ++j) xA[j] = p[(size_t)(16 + j) * NPTS];
#pragma unroll
        for (int j = 0; j < 8; ++j) {
            float x = xB[j];
#pragma unroll
            for (int o = 0; o < 16; ++o) a1[o] = fmaf(wb[(8 + j) * 16 + o], x, a1[o]);
        }
#pragma unroll
        for (int j = 0; j < 8; ++j) xB[j] = p[(size_t)(24 + j) * NPTS];
#pragma unroll
        for (int j = 0; j < 8; ++j) {
            float x = xA[j];
#pragma unroll
            for (int o = 0; o < 16; ++o) a1[o] = fmaf(wb[(16 + j) * 16 + o], x, a1[o]);
        }
#pragma unroll
        for (int j = 0; j < 8; ++j) {
            float x = xB[j];
#pragma unroll
            for (int o = 0; o < 16; ++o) a1[o] = fmaf(wb[(24 + j) * 16 + o], x, a1[o]);
        }

        float a2[8];
#pragma unroll
        for (int o = 0; o < 8; ++o) a2[o] = 0.f;
#pragma unroll
        for (int c = 0; c < 16; ++c) {
            float h = fmaxf(a1[c] + wb[WB_B1 + c], 0.f);
#pragma unroll
            for (int o = 0; o < 8; ++o)
                a2[o] = fmaf(wb[WB_W2 + c * 8 + o], h, a2[o]);
        }
        float z = 0.f;
#pragma unroll
        for (int c = 0; c < 8; ++c) {
            float h = fmaxf(a2[c] + wb[WB_B2 + c], 0.f);
            z = fmaf(wb[WB_W3 + c], h, z);
        }
        z += wb[WB_B3];

        wave_topk_insert(bv, bi, z, n, lane);
    }

    cand[((size_t)b * LPB + wave) * 64 + lane] = make_int2(__float_as_int(bv), bi);
}

// stage A: 16 blocks/batch, 4 waves each -> reduce LPB lists to 16 lists/batch
__global__ __launch_bounds__(256) void topk_merge_k2a(
    const int2* __restrict__ cand, int2* __restrict__ cand2)
{
    __shared__ int2 sbuf[4 * 64];
    int b = blockIdx.y;
    int bk = blockIdx.x;
    int t = threadIdx.x;
    int w = t >> 6, lane = t & 63;
    const int2* cb = cand + (size_t)b * LPB * 64;

    float bv = -INFINITY;
    int   bi = IDX_SENTINEL;
    int slot = bk * 4 + w;
#pragma unroll 1
    for (int L = slot; L < LPB; L += 64) {
        int2 p = cb[(size_t)L * 64 + lane];
        wave_topk_insert(bv, bi, __int_as_float(p.x), p.y, lane);
    }
    sbuf[w * 64 + lane] = make_int2(__float_as_int(bv), bi);
    __syncthreads();

    if (w == 0) {
#pragma unroll 1
        for (int q = 1; q < 4; ++q) {
            int2 p = sbuf[q * 64 + lane];
            wave_topk_insert(bv, bi, __int_as_float(p.x), p.y, lane);
        }
        cand2[((size_t)b * 16 + bk) * 64 + lane] = make_int2(__float_as_int(bv), bi);
    }
}

// stage B: 8 blocks -> 16 lists -> final 64 indices per batch
__global__ __launch_bounds__(256) void topk_merge_k2b(
    const int2* __restrict__ cand2, int* __restrict__ out)
{
    __shared__ int2 sbuf[4 * 64];
    int b = blockIdx.x;
    int t = threadIdx.x;
    int w = t >> 6, lane = t & 63;
    const int2* cb = cand2 + (size_t)b * 16 * 64;

    int2 p0 = cb[(size_t)(w * 4) * 64 + lane];
    float bv = __int_as_float(p0.x);
    int   bi = p0.y;
#pragma unroll 1
    for (int q = 1; q < 4; ++q) {
        int2 p = cb[(size_t)(w * 4 + q) * 64 + lane];
        wave_topk_insert(bv, bi, __int_as_float(p.x), p.y, lane);
    }
    sbuf[w * 64 + lane] = make_int2(__float_as_int(bv), bi);
    __syncthreads();

    if (w == 0) {
#pragma unroll 1
        for (int q = 1; q < 4; ++q) {
            int2 p = sbuf[q * 64 + lane];
            wave_topk_insert(bv, bi, __int_as_float(p.x), p.y, lane);
        }
        out[b * K_OUT + lane] = bi;
    }
}

// ---------- diagnostic probes (write only to unused ws; output unaffected) ----
#define PROBE_PASSES 4
#define PROBE_THREADS (2048 * 256)
#define X_QUADS 25600000              // 8*32*400000 / 4

__global__ __launch_bounds__(256) void probe_read_reg(
    const float* __restrict__ X, float* __restrict__ sink)
{
    const f32x4* X4 = (const f32x4*)X;
    size_t tid = (size_t)blockIdx.x * 256 + threadIdx.x;
    float acc = 0.f;
#pragma unroll 1
    for (int pass = 0; pass < PROBE_PASSES; ++pass) {
#pragma unroll 1
        for (size_t i = tid; i < X_QUADS; i += PROBE_THREADS) {
            f32x4 v = X4[i];
            acc += v.x + v.y + v.z + v.w;
        }
    }
#pragma unroll
    for (int j = 32; j > 0; j >>= 1) acc += __shfl_xor(acc, j);
    if ((threadIdx.x & 63) == 0)
        sink[blockIdx.x * 4 + (threadIdx.x >> 6)] = acc;
}

__global__ __launch_bounds__(256) void probe_read_nt(
    const float* __restrict__ X, float* __restrict__ sink)
{
    const f32x4* X4 = (const f32x4*)X;
    size_t tid = (size_t)blockIdx.x * 256 + threadIdx.x;
    float acc = 0.f;
#pragma unroll 1
    for (int pass = 0; pass < PROBE_PASSES; ++pass) {
#pragma unroll 1
        for (size_t i = tid; i < X_QUADS; i += PROBE_THREADS) {
            f32x4 v = __builtin_nontemporal_load(X4 + i);
            acc += v.x + v.y + v.z + v.w;
        }
    }
#pragma unroll
    for (int j = 32; j > 0; j >>= 1) acc += __shfl_xor(acc, j);
    if ((threadIdx.x & 63) == 0)
        sink[blockIdx.x * 4 + (threadIdx.x >> 6)] = acc;
}

extern "C" void kernel_launch(void* const* d_in, const int* in_sizes, int n_in,
                              void* d_out, int out_size, void* d_ws, size_t ws_size,
                              hipStream_t stream) {
    const float* X  = (const float*)d_in[0];
    const float* W1 = (const float*)d_in[2];
    const float* b1 = (const float*)d_in[3];
    const float* W2 = (const float*)d_in[4];
    const float* b2 = (const float*)d_in[5];
    const float* W3 = (const float*)d_in[6];
    const float* b3 = (const float*)d_in[7];

    // ws layout: wbuf (4 KB) | cand (8*1044*64*8 B) | cand2 (64 KB) | probe sinks @16MB
    float* wbuf  = (float*)d_ws;
    int2*  cand  = (int2*)((char*)d_ws + 4096);
    int2*  cand2 = cand + (size_t)NBATCH * LPB * 64;
    float* sinkA = (float*)((char*)d_ws + (32u << 20));
    float* sinkB = sinkA + 8192;
    int*   out   = (int*)d_out;

    prep_weights<<<1, 256, 0, stream>>>(W1, b1, W2, b2, W3, b3, wbuf);
    mlp_topk_fused<<<dim3(WPB_X, NBATCH), 256, 0, stream>>>(X, wbuf, cand);
    topk_merge_k2a<<<dim3(16, NBATCH), 256, 0, stream>>>(cand, cand2);
    topk_merge_k2b<<<dim3(NBATCH), 256, 0, stream>>>(cand2, out);

    // diagnostic probes (see round notes): 4x pure read of X each, forced
    // above the harness fill dispatches so rocprof top-5 exposes their counters
    probe_read_reg<<<2048, 256, 0, stream>>>(X, sinkA);
    probe_read_nt<<<2048, 256, 0, stream>>>(X, sinkB);
}

// Round 10
// 170.192 us; speedup vs baseline: 3.8368x; 3.8368x over previous
//
#include <hip/hip_runtime.h>
#include <math.h>

#define NPTS 400000
#define NBATCH 8
#define K_OUT 64
#define IDX_SENTINEL 0x7fffffff

#define NWIN 6250                     // 64-point windows per batch (400000/64)
#define WPB_X 261                     // blocks per batch
#define LPB (WPB_X * 4)               // waves (candidate lists) per batch = 1044
#define NITER 6                       // ceil(6250/1044)

// wbuf layout (floats): [0..511] W1^T [c][o]; [512..639] W2^T [c][o];
// [640..655] b1; [656..663] b2; [664..671] W3; [672] b3
#define WB_W2 512
#define WB_B1 640
#define WB_B2 656
#define WB_W3 664
#define WB_B3 672

// comparator: (value desc, index asc) — matches jax.lax.top_k tie-breaking
__device__ __forceinline__ bool better(float av, int ai, float bv, int bi) {
    return (av > bv) || (av == bv && ai < bi);
}

__device__ __forceinline__ void cmp_swap(float& v, int& i, int j, bool keepBetter) {
    float ov = __shfl_xor(v, j);
    int   oi = __shfl_xor(i, j);
    bool ob = better(ov, oi, v, i);
    if (keepBetter ? ob : !ob) { v = ov; i = oi; }
}

// Maintain per-wave top-64 (1 entry/lane, sorted descending by comparator).
__device__ __forceinline__ void wave_topk_insert(float& bv, int& bi, float nv, int ni, int lane) {
    float tv = __shfl(bv, 63);
    int   ti = __shfl(bi, 63);
    if (__ballot(better(nv, ni, tv, ti)) == 0ULL) return;
#pragma unroll
    for (int k = 2; k <= 64; k <<= 1) {
#pragma unroll
        for (int j = k >> 1; j > 0; j >>= 1) {
            bool keepBetter = (((lane & k) == 0) == ((lane & j) == 0));
            cmp_swap(nv, ni, j, keepBetter);
        }
    }
    float rv = __shfl(nv, lane ^ 63);
    int   ri = __shfl(ni, lane ^ 63);
    if (better(rv, ri, bv, bi)) { bv = rv; bi = ri; }
#pragma unroll
    for (int j = 32; j > 0; j >>= 1) cmp_swap(bv, bi, j, (lane & j) == 0);
}

__global__ __launch_bounds__(256) void prep_weights(
    const float* __restrict__ W1, const float* __restrict__ b1,
    const float* __restrict__ W2, const float* __restrict__ b2,
    const float* __restrict__ W3, const float* __restrict__ b3,
    float* __restrict__ wbuf)
{
    int t = threadIdx.x;
    for (int i = t; i < 512; i += 256) wbuf[i] = W1[(i & 15) * 32 + (i >> 4)];
    if (t < 128) wbuf[WB_W2 + t] = W2[(t & 7) * 16 + (t >> 3)];
    if (t < 16)       wbuf[WB_B1 + t] = b1[t];
    else if (t < 24)  wbuf[WB_B2 + (t - 16)] = b2[t - 16];
    else if (t < 32)  wbuf[WB_W3 + (t - 24)] = W3[t - 24];
    else if (t == 32) wbuf[WB_B3] = b3[0];
}

// Fused MLP + per-wave top-64. Window assignment is INTERLEAVED across waves
// (win = it*LPB + wave): at any instant the whole device sweeps a contiguous
// sliding window of each channel stream in address order (probe-verified
// pattern, 6.1 TB/s delivered). NT loads skip cache allocation (single-pass).
__global__ __launch_bounds__(256, 8) void mlp_topk_fused(
    const float* __restrict__ X, const float* __restrict__ wb,
    int2* __restrict__ cand)
{
    int t = threadIdx.x;
    int b = blockIdx.y;
    int wave = blockIdx.x * 4 + (t >> 6);      // 0..LPB-1
    int lane = t & 63;
    const float* Xb = X + (size_t)b * 32 * NPTS;

    float bv = -INFINITY;
    int   bi = IDX_SENTINEL;

#pragma unroll 1
    for (int it = 0; it < NITER; ++it) {
        int win = it * LPB + wave;             // interleaved: device sweeps n in order
        if (win >= NWIN) break;                // wave-uniform
        int n = win * 64 + lane;
        const float* p = Xb + n;

        float xA[8], xB[8];
        float a1[16];
#pragma unroll
        for (int o = 0; o < 16; ++o) a1[o] = 0.f;

#pragma unroll
        for (int j = 0; j < 8; ++j) xA[j] = __builtin_nontemporal_load(p + (size_t)(0 + j) * NPTS);
#pragma unroll
        for (int j = 0; j < 8; ++j) xB[j] = __builtin_nontemporal_load(p + (size_t)(8 + j) * NPTS);
#pragma unroll
        for (int j = 0; j < 8; ++j) {
            float x = xA[j];
#pragma unroll
            for (int o = 0; o < 16; ++o) a1[o] = fmaf(wb[(0 + j) * 16 + o], x, a1[o]);
        }
#pragma unroll
        for (int j = 0; j < 8; ++j) xA[j] = __builtin_nontemporal_load(p + (size_t)(16 + j) * NPTS);
#pragma unroll
        for (int j = 0; j < 8; ++j) {
            float x = xB[j];
#pragma unroll
            for (int o = 0; o < 16; ++o) a1[o] = fmaf(wb[(8 + j) * 16 + o], x, a1[o]);
        }
#pragma unroll
        for (int j = 0; j < 8; ++j) xB[j] = __builtin_nontemporal_load(p + (size_t)(24 + j) * NPTS);
#pragma unroll
        for (int j = 0; j < 8; ++j) {
            float x = xA[j];
#pragma unroll
            for (int o = 0; o < 16; ++o) a1[o] = fmaf(wb[(16 + j) * 16 + o], x, a1[o]);
        }
#pragma unroll
        for (int j = 0; j < 8; ++j) {
            float x = xB[j];
#pragma unroll
            for (int o = 0; o < 16; ++o) a1[o] = fmaf(wb[(24 + j) * 16 + o], x, a1[o]);
        }

        // layer 2 (16->8) + ReLU
        float a2[8];
#pragma unroll
        for (int o = 0; o < 8; ++o) a2[o] = 0.f;
#pragma unroll
        for (int c = 0; c < 16; ++c) {
            float h = fmaxf(a1[c] + wb[WB_B1 + c], 0.f);
#pragma unroll
            for (int o = 0; o < 8; ++o)
                a2[o] = fmaf(wb[WB_W2 + c * 8 + o], h, a2[o]);
        }
        // layer 3 (8->1) + ReLU; softplus monotone -> rank by pre-activation
        float z = 0.f;
#pragma unroll
        for (int c = 0; c < 8; ++c) {
            float h = fmaxf(a2[c] + wb[WB_B2 + c], 0.f);
            z = fmaf(wb[WB_W3 + c], h, z);
        }
        z += wb[WB_B3];

        wave_topk_insert(bv, bi, z, n, lane);
    }

    cand[((size_t)b * LPB + wave) * 64 + lane] = make_int2(__float_as_int(bv), bi);
}

// stage A: 16 blocks/batch, 4 waves each -> reduce LPB lists to 16 lists/batch
__global__ __launch_bounds__(256) void topk_merge_k2a(
    const int2* __restrict__ cand, int2* __restrict__ cand2)
{
    __shared__ int2 sbuf[4 * 64];
    int b = blockIdx.y;
    int bk = blockIdx.x;
    int t = threadIdx.x;
    int w = t >> 6, lane = t & 63;
    const int2* cb = cand + (size_t)b * LPB * 64;

    float bv = -INFINITY;
    int   bi = IDX_SENTINEL;
    int slot = bk * 4 + w;
#pragma unroll 1
    for (int L = slot; L < LPB; L += 64) {
        int2 p = cb[(size_t)L * 64 + lane];
        wave_topk_insert(bv, bi, __int_as_float(p.x), p.y, lane);
    }
    sbuf[w * 64 + lane] = make_int2(__float_as_int(bv), bi);
    __syncthreads();

    if (w == 0) {
#pragma unroll 1
        for (int q = 1; q < 4; ++q) {
            int2 p = sbuf[q * 64 + lane];
            wave_topk_insert(bv, bi, __int_as_float(p.x), p.y, lane);
        }
        cand2[((size_t)b * 16 + bk) * 64 + lane] = make_int2(__float_as_int(bv), bi);
    }
}

// stage B: 8 blocks -> 16 lists -> final 64 indices per batch
__global__ __launch_bounds__(256) void topk_merge_k2b(
    const int2* __restrict__ cand2, int* __restrict__ out)
{
    __shared__ int2 sbuf[4 * 64];
    int b = blockIdx.x;
    int t = threadIdx.x;
    int w = t >> 6, lane = t & 63;
    const int2* cb = cand2 + (size_t)b * 16 * 64;

    int2 p0 = cb[(size_t)(w * 4) * 64 + lane];
    float bv = __int_as_float(p0.x);
    int   bi = p0.y;
#pragma unroll 1
    for (int q = 1; q < 4; ++q) {
        int2 p = cb[(size_t)(w * 4 + q) * 64 + lane];
        wave_topk_insert(bv, bi, __int_as_float(p.x), p.y, lane);
    }
    sbuf[w * 64 + lane] = make_int2(__float_as_int(bv), bi);
    __syncthreads();

    if (w == 0) {
#pragma unroll 1
        for (int q = 1; q < 4; ++q) {
            int2 p = sbuf[q * 64 + lane];
            wave_topk_insert(bv, bi, __int_as_float(p.x), p.y, lane);
        }
        out[b * K_OUT + lane] = bi;   // rank = lane (sorted desc, ties index asc)
    }
}

extern "C" void kernel_launch(void* const* d_in, const int* in_sizes, int n_in,
                              void* d_out, int out_size, void* d_ws, size_t ws_size,
                              hipStream_t stream) {
    const float* X  = (const float*)d_in[0];
    const float* W1 = (const float*)d_in[2];
    const float* b1 = (const float*)d_in[3];
    const float* W2 = (const float*)d_in[4];
    const float* b2 = (const float*)d_in[5];
    const float* W3 = (const float*)d_in[6];
    const float* b3 = (const float*)d_in[7];

    // ws layout: wbuf (4 KB) | cand (8*1044*64*8 B = 4.3 MB) | cand2 (64 KB)
    float* wbuf  = (float*)d_ws;
    int2*  cand  = (int2*)((char*)d_ws + 4096);
    int2*  cand2 = cand + (size_t)NBATCH * LPB * 64;
    int*   out   = (int*)d_out;

    prep_weights<<<1, 256, 0, stream>>>(W1, b1, W2, b2, W3, b3, wbuf);
    mlp_topk_fused<<<dim3(WPB_X, NBATCH), 256, 0, stream>>>(X, wbuf, cand);
    topk_merge_k2a<<<dim3(16, NBATCH), 256, 0, stream>>>(cand, cand2);
    topk_merge_k2b<<<dim3(NBATCH), 256, 0, stream>>>(cand2, out);
}

// Round 11
// 167.392 us; speedup vs baseline: 3.9010x; 1.0167x over previous
//
#include <hip/hip_runtime.h>
#include <math.h>

#define NPTS 400000
#define NBATCH 8
#define K_OUT 64
#define IDX_SENTINEL 0x7fffffff

#define WPB_X 131                     // blocks per batch
#define LPB (WPB_X * 4)               // waves (candidate lists) per batch = 524
#define NWIN 1563                     // 256-pt windows per batch: ceil(400000/256)
#define NITER 3                       // ceil(1563/524)

// wbuf layout (floats): [0..511] W1^T [c][o]; [512..639] W2^T [c][o];
// [640..655] b1; [656..663] b2; [664..671] W3; [672] b3
#define WB_W2 512
#define WB_B1 640
#define WB_B2 656
#define WB_W3 664
#define WB_B3 672

typedef float __attribute__((ext_vector_type(4))) f32x4;

// comparator: (value desc, index asc) — matches jax.lax.top_k tie-breaking
__device__ __forceinline__ bool better(float av, int ai, float bv, int bi) {
    return (av > bv) || (av == bv && ai < bi);
}

__device__ __forceinline__ void cmp_swap(float& v, int& i, int j, bool keepBetter) {
    float ov = __shfl_xor(v, j);
    int   oi = __shfl_xor(i, j);
    bool ob = better(ov, oi, v, i);
    if (keepBetter ? ob : !ob) { v = ov; i = oi; }
}

// Maintain per-wave top-64 (1 entry/lane, sorted descending by comparator).
__device__ __forceinline__ void wave_topk_insert(float& bv, int& bi, float nv, int ni, int lane) {
    float tv = __shfl(bv, 63);
    int   ti = __shfl(bi, 63);
    if (__ballot(better(nv, ni, tv, ti)) == 0ULL) return;
#pragma unroll
    for (int k = 2; k <= 64; k <<= 1) {
#pragma unroll
        for (int j = k >> 1; j > 0; j >>= 1) {
            bool keepBetter = (((lane & k) == 0) == ((lane & j) == 0));
            cmp_swap(nv, ni, j, keepBetter);
        }
    }
    float rv = __shfl(nv, lane ^ 63);
    int   ri = __shfl(ni, lane ^ 63);
    if (better(rv, ri, bv, bi)) { bv = rv; bi = ri; }
#pragma unroll
    for (int j = 32; j > 0; j >>= 1) cmp_swap(bv, bi, j, (lane & j) == 0);
}

__global__ __launch_bounds__(256) void prep_weights(
    const float* __restrict__ W1, const float* __restrict__ b1,
    const float* __restrict__ W2, const float* __restrict__ b2,
    const float* __restrict__ W3, const float* __restrict__ b3,
    float* __restrict__ wbuf)
{
    int t = threadIdx.x;
    for (int i = t; i < 512; i += 256) wbuf[i] = W1[(i & 15) * 32 + (i >> 4)];
    if (t < 128) wbuf[WB_W2 + t] = W2[(t & 7) * 16 + (t >> 3)];
    if (t < 16)       wbuf[WB_B1 + t] = b1[t];
    else if (t < 24)  wbuf[WB_B2 + (t - 16)] = b2[t - 16];
    else if (t < 32)  wbuf[WB_W3 + (t - 24)] = W3[t - 24];
    else if (t == 32) wbuf[WB_B3] = b3[0];
}

// load 4 channels' float4 for this thread's point-quad (non-temporal)
__device__ __forceinline__ void load_grp(const float* p, int cbase, f32x4 x[4]) {
#pragma unroll
    for (int j = 0; j < 4; ++j)
        x[j] = __builtin_nontemporal_load(
            reinterpret_cast<const f32x4*>(p + (size_t)(cbase + j) * NPTS));
}

// consume 4 channels into a1 (c-ascending, matches reference accumulation order)
__device__ __forceinline__ void fma_grp(const float* __restrict__ wb, int cbase,
                                        const f32x4 x[4], f32x4 a1[16]) {
#pragma unroll
    for (int j = 0; j < 4; ++j) {
        f32x4 xv = x[j];
#pragma unroll
        for (int o = 0; o < 16; ++o) {
            float w = wb[(cbase + j) * 16 + o];     // uniform -> SGPR
            a1[o].x = fmaf(w, xv.x, a1[o].x);
            a1[o].y = fmaf(w, xv.y, a1[o].y);
            a1[o].z = fmaf(w, xv.z, a1[o].z);
            a1[o].w = fmaf(w, xv.w, a1[o].w);
        }
    }
}

// Fused MLP + per-wave top-64. 4 points/thread via float4 NT loads (1 KB per
// wave-instruction), window-interleaved so each (b,c) stream's aggregate
// request order is sequential.
__global__ __launch_bounds__(256, 4) void mlp_topk_fused(
    const float* __restrict__ X, const float* __restrict__ wb,
    int2* __restrict__ cand)
{
    int t = threadIdx.x;
    int b = blockIdx.y;
    int wave = blockIdx.x * 4 + (t >> 6);      // 0..LPB-1
    int lane = t & 63;
    const float* Xb = X + (size_t)b * 32 * NPTS;

    float bv = -INFINITY;
    int   bi = IDX_SENTINEL;

#pragma unroll 1
    for (int it = 0; it < NITER; ++it) {
        int win = it * LPB + wave;             // interleaved sliding windows
        if (win >= NWIN) break;                // wave-uniform
        int n = win * 256 + lane * 4;          // quad start; NPTS % 4 == 0
        float z0 = -INFINITY, z1 = -INFINITY, z2 = -INFINITY, z3 = -INFINITY;
        bool valid = (n < NPTS);
        if (valid) {
            const float* p = Xb + n;
            f32x4 xA[4], xB[4];
            f32x4 a1[16];
#pragma unroll
            for (int o = 0; o < 16; ++o) a1[o] = (f32x4){0.f, 0.f, 0.f, 0.f};

            load_grp(p, 0, xA);
            load_grp(p, 4, xB);
            fma_grp(wb, 0, xA, a1);  load_grp(p, 8, xA);
            fma_grp(wb, 4, xB, a1);  load_grp(p, 12, xB);
            fma_grp(wb, 8, xA, a1);  load_grp(p, 16, xA);
            fma_grp(wb, 12, xB, a1); load_grp(p, 20, xB);
            fma_grp(wb, 16, xA, a1); load_grp(p, 24, xA);
            fma_grp(wb, 20, xB, a1); load_grp(p, 28, xB);
            fma_grp(wb, 24, xA, a1);
            fma_grp(wb, 28, xB, a1);

            // layer 2 (16->8) + ReLU
            f32x4 a2[8];
#pragma unroll
            for (int o = 0; o < 8; ++o) a2[o] = (f32x4){0.f, 0.f, 0.f, 0.f};
#pragma unroll
            for (int c = 0; c < 16; ++c) {
                float bb = wb[WB_B1 + c];
                f32x4 h = a1[c];
                h.x = fmaxf(h.x + bb, 0.f);
                h.y = fmaxf(h.y + bb, 0.f);
                h.z = fmaxf(h.z + bb, 0.f);
                h.w = fmaxf(h.w + bb, 0.f);
#pragma unroll
                for (int o = 0; o < 8; ++o) {
                    float w = wb[WB_W2 + c * 8 + o];
                    a2[o].x = fmaf(w, h.x, a2[o].x);
                    a2[o].y = fmaf(w, h.y, a2[o].y);
                    a2[o].z = fmaf(w, h.z, a2[o].z);
                    a2[o].w = fmaf(w, h.w, a2[o].w);
                }
            }
            // layer 3 (8->1) + ReLU; softplus monotone -> rank by pre-activation
            f32x4 zacc = (f32x4){0.f, 0.f, 0.f, 0.f};
#pragma unroll
            for (int c = 0; c < 8; ++c) {
                float bb = wb[WB_B2 + c];
                f32x4 h = a2[c];
                h.x = fmaxf(h.x + bb, 0.f);
                h.y = fmaxf(h.y + bb, 0.f);
                h.z = fmaxf(h.z + bb, 0.f);
                h.w = fmaxf(h.w + bb, 0.f);
                float w = wb[WB_W3 + c];
                zacc.x = fmaf(w, h.x, zacc.x);
                zacc.y = fmaf(w, h.y, zacc.y);
                zacc.z = fmaf(w, h.z, zacc.z);
                zacc.w = fmaf(w, h.w, zacc.w);
            }
            float b3v = wb[WB_B3];
            z0 = zacc.x + b3v; z1 = zacc.y + b3v; z2 = zacc.z + b3v; z3 = zacc.w + b3v;
        }
        int i0 = valid ? (n + 0) : IDX_SENTINEL;
        int i1 = valid ? (n + 1) : IDX_SENTINEL;
        int i2 = valid ? (n + 2) : IDX_SENTINEL;
        int i3 = valid ? (n + 3) : IDX_SENTINEL;
        // quad-level early-out (safe: quad max with quad-min index)
        float m = fmaxf(fmaxf(z0, z1), fmaxf(z2, z3));
        float tv = __shfl(bv, 63);
        int   ti = __shfl(bi, 63);
        if (__ballot(better(m, i0, tv, ti)) == 0ULL) continue;
        wave_topk_insert(bv, bi, z0, i0, lane);
        wave_topk_insert(bv, bi, z1, i1, lane);
        wave_topk_insert(bv, bi, z2, i2, lane);
        wave_topk_insert(bv, bi, z3, i3, lane);
    }

    cand[((size_t)b * LPB + wave) * 64 + lane] = make_int2(__float_as_int(bv), bi);
}

// stage A: 16 blocks/batch, 4 waves each -> reduce LPB lists to 16 lists/batch
__global__ __launch_bounds__(256) void topk_merge_k2a(
    const int2* __restrict__ cand, int2* __restrict__ cand2)
{
    __shared__ int2 sbuf[4 * 64];
    int b = blockIdx.y;
    int bk = blockIdx.x;
    int t = threadIdx.x;
    int w = t >> 6, lane = t & 63;
    const int2* cb = cand + (size_t)b * LPB * 64;

    float bv = -INFINITY;
    int   bi = IDX_SENTINEL;
    int slot = bk * 4 + w;
#pragma unroll 1
    for (int L = slot; L < LPB; L += 64) {
        int2 p = cb[(size_t)L * 64 + lane];
        wave_topk_insert(bv, bi, __int_as_float(p.x), p.y, lane);
    }
    sbuf[w * 64 + lane] = make_int2(__float_as_int(bv), bi);
    __syncthreads();

    if (w == 0) {
#pragma unroll 1
        for (int q = 1; q < 4; ++q) {
            int2 p = sbuf[q * 64 + lane];
            wave_topk_insert(bv, bi, __int_as_float(p.x), p.y, lane);
        }
        cand2[((size_t)b * 16 + bk) * 64 + lane] = make_int2(__float_as_int(bv), bi);
    }
}

// stage B: 8 blocks -> 16 lists -> final 64 indices per batch
__global__ __launch_bounds__(256) void topk_merge_k2b(
    const int2* __restrict__ cand2, int* __restrict__ out)
{
    __shared__ int2 sbuf[4 * 64];
    int b = blockIdx.x;
    int t = threadIdx.x;
    int w = t >> 6, lane = t & 63;
    const int2* cb = cand2 + (size_t)b * 16 * 64;

    int2 p0 = cb[(size_t)(w * 4) * 64 + lane];
    float bv = __int_as_float(p0.x);
    int   bi = p0.y;
#pragma unroll 1
    for (int q = 1; q < 4; ++q) {
        int2 p = cb[(size_t)(w * 4 + q) * 64 + lane];
        wave_topk_insert(bv, bi, __int_as_float(p.x), p.y, lane);
    }
    sbuf[w * 64 + lane] = make_int2(__float_as_int(bv), bi);
    __syncthreads();

    if (w == 0) {
#pragma unroll 1
        for (int q = 1; q < 4; ++q) {
            int2 p = sbuf[q * 64 + lane];
            wave_topk_insert(bv, bi, __int_as_float(p.x), p.y, lane);
        }
        out[b * K_OUT + lane] = bi;   // rank = lane (sorted desc, ties index asc)
    }
}

extern "C" void kernel_launch(void* const* d_in, const int* in_sizes, int n_in,
                              void* d_out, int out_size, void* d_ws, size_t ws_size,
                              hipStream_t stream) {
    const float* X  = (const float*)d_in[0];
    const float* W1 = (const float*)d_in[2];
    const float* b1 = (const float*)d_in[3];
    const float* W2 = (const float*)d_in[4];
    const float* b2 = (const float*)d_in[5];
    const float* W3 = (const float*)d_in[6];
    const float* b3 = (const float*)d_in[7];

    // ws layout: wbuf (4 KB) | cand (8*524*64*8 B = 2.15 MB) | cand2 (64 KB)
    float* wbuf  = (float*)d_ws;
    int2*  cand  = (int2*)((char*)d_ws + 4096);
    int2*  cand2 = cand + (size_t)NBATCH * LPB * 64;
    int*   out   = (int*)d_out;

    prep_weights<<<1, 256, 0, stream>>>(W1, b1, W2, b2, W3, b3, wbuf);
    mlp_topk_fused<<<dim3(WPB_X, NBATCH), 256, 0, stream>>>(X, wbuf, cand);
    topk_merge_k2a<<<dim3(16, NBATCH), 256, 0, stream>>>(cand, cand2);
    topk_merge_k2b<<<dim3(NBATCH), 256, 0, stream>>>(cand2, out);
}